// Round 6
// baseline (809.688 us; speedup 1.0000x reference)
//
#include <hip/hip_runtime.h>

#define DIM 64
#define NGRAPH 128
#define GATTR 4
#define BN_EPS 1e-5f
#define BUCKET_SHIFT 7
#define BUCKET 128   // nodes per bucket; NBUCK = ceil(N/128) <= 1024

// ---------------- CSR build: bucketed counting sort by dst ----------------

// Phase A: histogram of edges per bucket (LDS-aggregated)
__global__ __launch_bounds__(256) void k_bhist(const int* __restrict__ dst,
                                               int* __restrict__ bcnt,
                                               int E, int nbuck) {
    __shared__ int lb[1024];
    for (int i = threadIdx.x; i < nbuck; i += 256) lb[i] = 0;
    __syncthreads();
    int stride = gridDim.x * 256;
    for (int e = blockIdx.x * 256 + threadIdx.x; e < E; e += stride)
        atomicAdd(&lb[dst[e] >> BUCKET_SHIFT], 1);
    __syncthreads();
    for (int i = threadIdx.x; i < nbuck; i += 256) {
        int v = lb[i];
        if (v) atomicAdd(&bcnt[i], v);
    }
}

// Phase B: exclusive scan of bucket counts (nbuck <= 1024), one block
__global__ __launch_bounds__(1024) void k_bscan(const int* __restrict__ bcnt,
                                                int* __restrict__ bbase,
                                                int* __restrict__ rowptr,
                                                int nbuck, int n, int E) {
    __shared__ int ws[1024];
    int tid = threadIdx.x;
    int v = (tid < nbuck) ? bcnt[tid] : 0;
    ws[tid] = v;
    __syncthreads();
    for (int off = 1; off < 1024; off <<= 1) {
        int t = (tid >= off) ? ws[tid - off] : 0;
        __syncthreads();
        ws[tid] += t;
        __syncthreads();
    }
    if (tid < nbuck) bbase[tid] = ws[tid] - v;  // exclusive
    if (tid == 0) { bbase[nbuck] = E; rowptr[n] = E; }
}

// Phase C: bin edges into bucket-contiguous (src,dst) pairs.
// 1 edge/thread, full grid (lesson from r5: atomic kernels need TLP not ILP).
// Writes for a bucket fall in a ~12KB window -> L2-absorbed, ~1x amplification.
__global__ __launch_bounds__(256) void k_bin(const int* __restrict__ src,
                                             const int* __restrict__ dst,
                                             const int* __restrict__ bbase,
                                             int* __restrict__ bwp,
                                             int2* __restrict__ pairs, int E) {
    int e = blockIdx.x * 256 + threadIdx.x;
    if (e >= E) return;
    int d = dst[e];
    int b = d >> BUCKET_SHIFT;
    int q = atomicAdd(&bwp[b], 1);
    pairs[bbase[b] + q] = make_int2(src[e], d);
}

// Phase D: per-bucket counting sort -> col + rowptr (one block per bucket)
__global__ __launch_bounds__(256) void k_bsort(const int2* __restrict__ pairs,
                                               const int* __restrict__ bbase,
                                               int* __restrict__ rowptr,
                                               int* __restrict__ col, int n) {
    __shared__ int lcnt[BUCKET];
    __shared__ int lofs[BUCKET];
    int b = blockIdx.x;
    int tid = threadIdx.x;
    int cbase = bbase[b];
    int ecnt = bbase[b + 1] - cbase;
    int node0 = b << BUCKET_SHIFT;
    int nn = min(BUCKET, n - node0);
    if (tid < BUCKET) lcnt[tid] = 0;
    __syncthreads();
    for (int i = tid; i < ecnt; i += 256)
        atomicAdd(&lcnt[pairs[cbase + i].y - node0], 1);
    __syncthreads();
    // exclusive scan of lcnt over BUCKET entries (Hillis-Steele in lofs)
    int v = (tid < BUCKET) ? lcnt[tid] : 0;
    if (tid < BUCKET) lofs[tid] = v;
    __syncthreads();
    for (int off = 1; off < BUCKET; off <<= 1) {
        int t = (tid < BUCKET && tid >= off) ? lofs[tid - off] : 0;
        __syncthreads();
        if (tid < BUCKET) lofs[tid] += t;
        __syncthreads();
    }
    int excl = (tid < BUCKET) ? (lofs[tid] - v) : 0;
    __syncthreads();
    if (tid < BUCKET) lofs[tid] = excl;       // write cursors
    if (tid < nn) rowptr[node0 + tid] = cbase + excl;
    __syncthreads();
    for (int i = tid; i < ecnt; i += 256) {
        int2 pr = pairs[cbase + i];
        int p = cbase + atomicAdd(&lofs[pr.y - node0], 1);
        col[p] = pr.x;
    }
}

// ---------------- mean aggregation ----------------
// One wave per node. lane = (g, p): g = edge slot (0..3), p = dim quad (0..15).

__global__ __launch_bounds__(256) void k_agg(const float* __restrict__ h,
                                             const int* __restrict__ row_ptr,
                                             const int* __restrict__ col,
                                             float* __restrict__ agg, int n) {
    int wid = (blockIdx.x * blockDim.x + threadIdx.x) >> 6;
    if (wid >= n) return;
    int lane = threadIdx.x & 63;
    int g = lane >> 4;   // edge slot
    int p = lane & 15;   // dim quad: dims 4p..4p+3
    int beg = row_ptr[wid], end = row_ptr[wid + 1];

    float ax = 0.f, ay = 0.f, az = 0.f, aw = 0.f;
    float bx = 0.f, by = 0.f, bz = 0.f, bw = 0.f;
    int j = beg + g;
    for (; j + 4 < end; j += 8) {
        int s0 = col[j];
        int s1 = col[j + 4];
        float4 v0 = ((const float4*)(h + (size_t)s0 * DIM))[p];
        float4 v1 = ((const float4*)(h + (size_t)s1 * DIM))[p];
        ax += v0.x; ay += v0.y; az += v0.z; aw += v0.w;
        bx += v1.x; by += v1.y; bz += v1.z; bw += v1.w;
    }
    if (j < end) {
        int s0 = col[j];
        float4 v0 = ((const float4*)(h + (size_t)s0 * DIM))[p];
        ax += v0.x; ay += v0.y; az += v0.z; aw += v0.w;
    }
    ax += bx; ay += by; az += bz; aw += bw;

#pragma unroll
    for (int m = 16; m <= 32; m <<= 1) {
        ax += __shfl_xor(ax, m, 64);
        ay += __shfl_xor(ay, m, 64);
        az += __shfl_xor(az, m, 64);
        aw += __shfl_xor(aw, m, 64);
    }

    if (g == 0) {
        float c = (float)(end - beg);
        float inv = 1.0f / fmaxf(c, 1.0f);
        float4 r;
        r.x = ax * inv; r.y = ay * inv; r.z = az * inv; r.w = aw * inv;
        ((float4*)(agg + (size_t)wid * DIM))[p] = r;
    }
}

// ---------------- fused linear (agg@Wl + bl + h@Wr) + BN(eval) + ReLU ----------------

__global__ __launch_bounds__(256) void k_xform(const float* __restrict__ agg,
                                               const float* __restrict__ h,
                                               const float* __restrict__ Wl,
                                               const float* __restrict__ bl,
                                               const float* __restrict__ Wr,
                                               const float* __restrict__ bng,
                                               const float* __restrict__ bnb,
                                               const float* __restrict__ bnm,
                                               const float* __restrict__ bnv,
                                               float* __restrict__ out, int n) {
    __shared__ float sWl[64 * 64];
    __shared__ float sWr[64 * 64];
    __shared__ float sA[64 * 64];
    __shared__ float sH[64 * 64];
    int tid = threadIdx.x;
    int base = blockIdx.x * 64;
    int rows = min(64, n - base);

    const float4* Wl4 = (const float4*)Wl;
    const float4* Wr4 = (const float4*)Wr;
    float4* sWl4 = (float4*)sWl;
    float4* sWr4 = (float4*)sWr;
    const float4* A4 = (const float4*)(agg + (size_t)base * DIM);
    const float4* H4 = (const float4*)(h + (size_t)base * DIM);
    float4* sA4 = (float4*)sA;
    float4* sH4 = (float4*)sH;
    for (int i = tid; i < 64 * 64 / 4; i += 256) {
        sWl4[i] = Wl4[i];
        sWr4[i] = Wr4[i];
        int row = i >> 4;
        float4 va = {0.f, 0.f, 0.f, 0.f}, vh = {0.f, 0.f, 0.f, 0.f};
        if (row < rows) { va = A4[i]; vh = H4[i]; }
        sA4[i] = va;
        sH4[i] = vh;
    }
    __syncthreads();

    int d = tid & 63;
    int nq = tid >> 6;
    float acc[16];
#pragma unroll
    for (int i = 0; i < 16; ++i) acc[i] = 0.f;

    for (int k = 0; k < 64; k += 4) {
        float wl0 = sWl[(k + 0) * 64 + d];
        float wl1 = sWl[(k + 1) * 64 + d];
        float wl2 = sWl[(k + 2) * 64 + d];
        float wl3 = sWl[(k + 3) * 64 + d];
        float wr0 = sWr[(k + 0) * 64 + d];
        float wr1 = sWr[(k + 1) * 64 + d];
        float wr2 = sWr[(k + 2) * 64 + d];
        float wr3 = sWr[(k + 3) * 64 + d];
#pragma unroll
        for (int i = 0; i < 16; ++i) {
            int nd = nq + 4 * i;
            const float4 a4 = *(const float4*)&sA[nd * 64 + k];
            const float4 h4 = *(const float4*)&sH[nd * 64 + k];
            acc[i] += a4.x * wl0 + a4.y * wl1 + a4.z * wl2 + a4.w * wl3
                    + h4.x * wr0 + h4.y * wr1 + h4.z * wr2 + h4.w * wr3;
        }
    }

    float scale = bng[d] / sqrtf(bnv[d] + BN_EPS);
    float shift = bnb[d];
    float mean = bnm[d];
    float bias = bl[d];
#pragma unroll
    for (int i = 0; i < 16; ++i) {
        int nd = nq + 4 * i;
        int node = base + nd;
        if (node < n) {
            float v = (acc[i] + bias - mean) * scale + shift;
            out[(size_t)node * DIM + d] = fmaxf(v, 0.f);
        }
    }
}

// ---------------- global mean pool (batch sorted) ----------------

__global__ __launch_bounds__(256) void k_pool(const float* __restrict__ h,
                                              const int* __restrict__ batch,
                                              float* __restrict__ gsum,
                                              int* __restrict__ gcnt, int n) {
    int nw = gridDim.x * 4;
    int w = blockIdx.x * 4 + (threadIdx.x >> 6);
    int lane = threadIdx.x & 63;
    int chunk = (n + nw - 1) / nw;
    int s = w * chunk, e = min(s + chunk, n);
    if (s >= e) return;
    int cur = batch[s];
    float acc = 0.f;
    int cnt = 0;
    for (int i = s; i < e; ++i) {
        int g = batch[i];
        if (g != cur) {
            atomicAdd(&gsum[cur * DIM + lane], acc);
            if (lane == 0) atomicAdd(&gcnt[cur], cnt);
            acc = 0.f; cnt = 0; cur = g;
        }
        acc += h[(size_t)i * DIM + lane];
        ++cnt;
    }
    atomicAdd(&gsum[cur * DIM + lane], acc);
    if (lane == 0) atomicAdd(&gcnt[cur], cnt);
}

// ---------------- classifier head ----------------

__global__ __launch_bounds__(256) void k_mlp(const float* __restrict__ gsum,
                                             const int* __restrict__ gcnt,
                                             const float* __restrict__ gattr,
                                             const float* __restrict__ W1,
                                             const float* __restrict__ b1,
                                             const float* __restrict__ W2,
                                             const float* __restrict__ b2,
                                             float* __restrict__ out) {
    __shared__ float emb[NGRAPH][DIM + GATTR];
    __shared__ float hid[NGRAPH][32];
    int tid = threadIdx.x;
    for (int i = tid; i < NGRAPH * DIM; i += 256) {
        int g = i >> 6, d = i & 63;
        float c = (float)gcnt[g];
        emb[g][d] = gsum[i] / fmaxf(c, 1.0f);
    }
    for (int i = tid; i < NGRAPH * GATTR; i += 256) {
        int g = i >> 2, d = i & 3;
        emb[g][DIM + d] = gattr[i];
    }
    __syncthreads();
    for (int t = tid; t < NGRAPH * 32; t += 256) {
        int g = t >> 5, j = t & 31;
        float a = b1[j];
        for (int k = 0; k < DIM + GATTR; ++k) a += emb[g][k] * W1[k * 32 + j];
        hid[g][j] = fmaxf(a, 0.f);
    }
    __syncthreads();
    {
        int g = tid >> 1, o = tid & 1;
        float a = b2[o];
        for (int k = 0; k < 32; ++k) a += hid[g][k] * W2[k * 2 + o];
        out[g * 2 + o] = a;
    }
}

extern "C" void kernel_launch(void* const* d_in, const int* in_sizes, int n_in,
                              void* d_out, int out_size, void* d_ws, size_t ws_size,
                              hipStream_t stream) {
    const float* x = (const float*)d_in[0];
    const int* ei = (const int*)d_in[1];
    const int* batch = (const int*)d_in[2];
    const float* gattr = (const float*)d_in[3];
    const int N = in_sizes[0] / DIM;
    const int E = in_sizes[1] / 2;
    const int* src = ei;
    const int* dst = ei + E;

    const float *Wl[3], *bl[3], *Wr[3], *bg[3], *bb[3], *bm[3], *bv[3];
    for (int l = 0; l < 3; ++l) {
        int base = 4 + l * 7;
        Wl[l] = (const float*)d_in[base + 0];
        bl[l] = (const float*)d_in[base + 1];
        Wr[l] = (const float*)d_in[base + 2];
        bg[l] = (const float*)d_in[base + 3];
        bb[l] = (const float*)d_in[base + 4];
        bm[l] = (const float*)d_in[base + 5];
        bv[l] = (const float*)d_in[base + 6];
    }
    const float* W1 = (const float*)d_in[25];
    const float* b1 = (const float*)d_in[26];
    const float* W2 = (const float*)d_in[27];
    const float* b2 = (const float*)d_in[28];

    char* ws = (char*)d_ws;
    size_t off = 0;
    auto alloc = [&](size_t bytes) -> char* {
        char* p = ws + off;
        off += (bytes + 255) & ~(size_t)255;
        return p;
    };
    int* rowptr = (int*)alloc((size_t)(N + 1) * 4);
    int* col = (int*)alloc((size_t)E * 4);
    float* aggb = (float*)alloc((size_t)N * DIM * 4);
    float* h0 = (float*)alloc((size_t)N * DIM * 4);
    float* h1 = (float*)alloc((size_t)N * DIM * 4);
    float* gsum = (float*)alloc((size_t)NGRAPH * DIM * 4);
    int* gcnt = (int*)alloc((size_t)NGRAPH * 4);
    int* bcnt = (int*)alloc(1024 * 4);
    int* bwp = (int*)alloc(1024 * 4);
    int* bbase = (int*)alloc(1025 * 4);
    int2* pairs = (int2*)aggb;  // scratch reuse: consumed before k_agg writes aggb
    (void)ws_size;

    const int nbuck = (N + BUCKET - 1) >> BUCKET_SHIFT;  // 782 for N=100000

    hipMemsetAsync(bcnt, 0, 1024 * 4, stream);
    hipMemsetAsync(bwp, 0, 1024 * 4, stream);
    hipMemsetAsync(gsum, 0, (size_t)NGRAPH * DIM * 4, stream);
    hipMemsetAsync(gcnt, 0, (size_t)NGRAPH * 4, stream);

    const int tpb = 256;
    k_bhist<<<256, tpb, 0, stream>>>(dst, bcnt, E, nbuck);
    k_bscan<<<1, 1024, 0, stream>>>(bcnt, bbase, rowptr, nbuck, N, E);
    k_bin<<<(E + tpb - 1) / tpb, tpb, 0, stream>>>(src, dst, bbase, bwp, pairs, E);
    k_bsort<<<nbuck, tpb, 0, stream>>>(pairs, bbase, rowptr, col, N);

    const float* hin = x;
    float* houts[3] = {h0, h1, h0};
    for (int l = 0; l < 3; ++l) {
        k_agg<<<(N * 64 + tpb - 1) / tpb, tpb, 0, stream>>>(hin, rowptr, col, aggb, N);
        k_xform<<<(N + 63) / 64, 256, 0, stream>>>(aggb, hin, Wl[l], bl[l], Wr[l],
                                                   bg[l], bb[l], bm[l], bv[l], houts[l], N);
        hin = houts[l];
    }

    k_pool<<<256, tpb, 0, stream>>>(hin, batch, gsum, gcnt, N);
    k_mlp<<<1, tpb, 0, stream>>>(gsum, gcnt, gattr, W1, b1, W2, b2, (float*)d_out);
}

// Round 7
// 640.130 us; speedup vs baseline: 1.2649x; 1.2649x over previous
//
#include <hip/hip_runtime.h>

#define DIM 64
#define NGRAPH 128
#define GATTR 4
#define BN_EPS 1e-5f
#define SCAN_CHUNK 4096  // 256 threads x 16 elems
#define NPASS 8          // dst-range passes for scatter write locality

// ---------------- CSR build ----------------

__global__ __launch_bounds__(256) void k_count(const int* __restrict__ dst,
                                               int* __restrict__ cnt, int E) {
    int e = blockIdx.x * blockDim.x + threadIdx.x;
    if (e < E) atomicAdd(&cnt[dst[e]], 1);
}

// Stage 1: per-block local exclusive scan (4096 elems) + block total
__global__ __launch_bounds__(256) void k_scan1(const int* __restrict__ cnt,
                                               int* __restrict__ rowptr,
                                               int* __restrict__ partials, int n) {
    __shared__ int ws[256];
    int tid = threadIdx.x;
    int base = blockIdx.x * SCAN_CHUNK + tid * 16;
    int v[16];
    int s = 0;
#pragma unroll
    for (int i = 0; i < 16; ++i) {
        int idx = base + i;
        v[i] = (idx < n) ? cnt[idx] : 0;
        s += v[i];
    }
    ws[tid] = s;
    __syncthreads();
    for (int off = 1; off < 256; off <<= 1) {
        int t = (tid >= off) ? ws[tid - off] : 0;
        __syncthreads();
        ws[tid] += t;
        __syncthreads();
    }
    int excl = (tid == 0) ? 0 : ws[tid - 1];
    if (tid == 255) partials[blockIdx.x] = ws[255];
#pragma unroll
    for (int i = 0; i < 16; ++i) {
        int idx = base + i;
        if (idx < n) rowptr[idx] = excl;
        excl += v[i];
    }
}

// Stage 2: exclusive scan of block totals (nb <= 256)
__global__ __launch_bounds__(256) void k_scan2(int* __restrict__ partials, int nb) {
    __shared__ int ws[256];
    int tid = threadIdx.x;
    int orig = (tid < nb) ? partials[tid] : 0;
    ws[tid] = orig;
    __syncthreads();
    for (int off = 1; off < 256; off <<= 1) {
        int t = (tid >= off) ? ws[tid - off] : 0;
        __syncthreads();
        ws[tid] += t;
        __syncthreads();
    }
    if (tid < nb) partials[tid] = ws[tid] - orig;  // exclusive
}

// Stage 3: add block offsets, fan out to rowptr and wp
__global__ __launch_bounds__(256) void k_scan3(int* __restrict__ rowptr,
                                               int* __restrict__ wp,
                                               const int* __restrict__ partials,
                                               int n, int E) {
    int base = blockIdx.x * SCAN_CHUNK;
    int off = partials[blockIdx.x];
    for (int i = threadIdx.x; i < SCAN_CHUNK; i += 256) {
        int idx = base + i;
        if (idx < n) {
            int v = rowptr[idx] + off;
            rowptr[idx] = v;
            wp[idx] = v;
        }
    }
    if (blockIdx.x == 0 && threadIdx.x == 0) rowptr[n] = E;
}

// Scatter restricted to dst in [lo, hi): col writes land in a ~640KB window
// per pass -> L2-resident, lines fill before writeback (kills the 16x write
// amplification seen with the unrestricted scatter).
__global__ __launch_bounds__(256) void k_scatter_pass(const int* __restrict__ src,
                                                      const int* __restrict__ dst,
                                                      int* __restrict__ wp,
                                                      int* __restrict__ col,
                                                      int E, int lo, int hi) {
    int e = blockIdx.x * blockDim.x + threadIdx.x;
    if (e >= E) return;
    int d = dst[e];
    if (d < lo || d >= hi) return;
    int p = atomicAdd(&wp[d], 1);
    col[p] = src[e];
}

// ---------------- mean aggregation ----------------
// One wave per node. lane = (g, p): g = edge slot (0..3), p = dim quad (0..15).

__global__ __launch_bounds__(256) void k_agg(const float* __restrict__ h,
                                             const int* __restrict__ row_ptr,
                                             const int* __restrict__ col,
                                             float* __restrict__ agg, int n) {
    int wid = (blockIdx.x * blockDim.x + threadIdx.x) >> 6;
    if (wid >= n) return;
    int lane = threadIdx.x & 63;
    int g = lane >> 4;   // edge slot
    int p = lane & 15;   // dim quad: dims 4p..4p+3
    int beg = row_ptr[wid], end = row_ptr[wid + 1];

    float ax = 0.f, ay = 0.f, az = 0.f, aw = 0.f;
    float bx = 0.f, by = 0.f, bz = 0.f, bw = 0.f;
    int j = beg + g;
    for (; j + 4 < end; j += 8) {
        int s0 = col[j];
        int s1 = col[j + 4];
        float4 v0 = ((const float4*)(h + (size_t)s0 * DIM))[p];
        float4 v1 = ((const float4*)(h + (size_t)s1 * DIM))[p];
        ax += v0.x; ay += v0.y; az += v0.z; aw += v0.w;
        bx += v1.x; by += v1.y; bz += v1.z; bw += v1.w;
    }
    if (j < end) {
        int s0 = col[j];
        float4 v0 = ((const float4*)(h + (size_t)s0 * DIM))[p];
        ax += v0.x; ay += v0.y; az += v0.z; aw += v0.w;
    }
    ax += bx; ay += by; az += bz; aw += bw;

#pragma unroll
    for (int m = 16; m <= 32; m <<= 1) {
        ax += __shfl_xor(ax, m, 64);
        ay += __shfl_xor(ay, m, 64);
        az += __shfl_xor(az, m, 64);
        aw += __shfl_xor(aw, m, 64);
    }

    if (g == 0) {
        float c = (float)(end - beg);
        float inv = 1.0f / fmaxf(c, 1.0f);
        float4 r;
        r.x = ax * inv; r.y = ay * inv; r.z = az * inv; r.w = aw * inv;
        ((float4*)(agg + (size_t)wid * DIM))[p] = r;
    }
}

// ---------------- fused linear (agg@Wl + bl + h@Wr) + BN(eval) + ReLU ----------------

__global__ __launch_bounds__(256) void k_xform(const float* __restrict__ agg,
                                               const float* __restrict__ h,
                                               const float* __restrict__ Wl,
                                               const float* __restrict__ bl,
                                               const float* __restrict__ Wr,
                                               const float* __restrict__ bng,
                                               const float* __restrict__ bnb,
                                               const float* __restrict__ bnm,
                                               const float* __restrict__ bnv,
                                               float* __restrict__ out, int n) {
    __shared__ float sWl[64 * 64];
    __shared__ float sWr[64 * 64];
    __shared__ float sA[64 * 64];
    __shared__ float sH[64 * 64];
    int tid = threadIdx.x;
    int base = blockIdx.x * 64;
    int rows = min(64, n - base);

    const float4* Wl4 = (const float4*)Wl;
    const float4* Wr4 = (const float4*)Wr;
    float4* sWl4 = (float4*)sWl;
    float4* sWr4 = (float4*)sWr;
    const float4* A4 = (const float4*)(agg + (size_t)base * DIM);
    const float4* H4 = (const float4*)(h + (size_t)base * DIM);
    float4* sA4 = (float4*)sA;
    float4* sH4 = (float4*)sH;
    for (int i = tid; i < 64 * 64 / 4; i += 256) {
        sWl4[i] = Wl4[i];
        sWr4[i] = Wr4[i];
        int row = i >> 4;
        float4 va = {0.f, 0.f, 0.f, 0.f}, vh = {0.f, 0.f, 0.f, 0.f};
        if (row < rows) { va = A4[i]; vh = H4[i]; }
        sA4[i] = va;
        sH4[i] = vh;
    }
    __syncthreads();

    int d = tid & 63;
    int nq = tid >> 6;
    float acc[16];
#pragma unroll
    for (int i = 0; i < 16; ++i) acc[i] = 0.f;

    for (int k = 0; k < 64; k += 4) {
        float wl0 = sWl[(k + 0) * 64 + d];
        float wl1 = sWl[(k + 1) * 64 + d];
        float wl2 = sWl[(k + 2) * 64 + d];
        float wl3 = sWl[(k + 3) * 64 + d];
        float wr0 = sWr[(k + 0) * 64 + d];
        float wr1 = sWr[(k + 1) * 64 + d];
        float wr2 = sWr[(k + 2) * 64 + d];
        float wr3 = sWr[(k + 3) * 64 + d];
#pragma unroll
        for (int i = 0; i < 16; ++i) {
            int nd = nq + 4 * i;
            const float4 a4 = *(const float4*)&sA[nd * 64 + k];
            const float4 h4 = *(const float4*)&sH[nd * 64 + k];
            acc[i] += a4.x * wl0 + a4.y * wl1 + a4.z * wl2 + a4.w * wl3
                    + h4.x * wr0 + h4.y * wr1 + h4.z * wr2 + h4.w * wr3;
        }
    }

    float scale = bng[d] / sqrtf(bnv[d] + BN_EPS);
    float shift = bnb[d];
    float mean = bnm[d];
    float bias = bl[d];
#pragma unroll
    for (int i = 0; i < 16; ++i) {
        int nd = nq + 4 * i;
        int node = base + nd;
        if (node < n) {
            float v = (acc[i] + bias - mean) * scale + shift;
            out[(size_t)node * DIM + d] = fmaxf(v, 0.f);
        }
    }
}

// ---------------- global mean pool (batch sorted) ----------------

__global__ __launch_bounds__(256) void k_pool(const float* __restrict__ h,
                                              const int* __restrict__ batch,
                                              float* __restrict__ gsum,
                                              int* __restrict__ gcnt, int n) {
    int nw = gridDim.x * 4;
    int w = blockIdx.x * 4 + (threadIdx.x >> 6);
    int lane = threadIdx.x & 63;
    int chunk = (n + nw - 1) / nw;
    int s = w * chunk, e = min(s + chunk, n);
    if (s >= e) return;
    int cur = batch[s];
    float acc = 0.f;
    int cnt = 0;
    for (int i = s; i < e; ++i) {
        int g = batch[i];
        if (g != cur) {
            atomicAdd(&gsum[cur * DIM + lane], acc);
            if (lane == 0) atomicAdd(&gcnt[cur], cnt);
            acc = 0.f; cnt = 0; cur = g;
        }
        acc += h[(size_t)i * DIM + lane];
        ++cnt;
    }
    atomicAdd(&gsum[cur * DIM + lane], acc);
    if (lane == 0) atomicAdd(&gcnt[cur], cnt);
}

// ---------------- classifier head ----------------

__global__ __launch_bounds__(256) void k_mlp(const float* __restrict__ gsum,
                                             const int* __restrict__ gcnt,
                                             const float* __restrict__ gattr,
                                             const float* __restrict__ W1,
                                             const float* __restrict__ b1,
                                             const float* __restrict__ W2,
                                             const float* __restrict__ b2,
                                             float* __restrict__ out) {
    __shared__ float emb[NGRAPH][DIM + GATTR];
    __shared__ float hid[NGRAPH][32];
    int tid = threadIdx.x;
    for (int i = tid; i < NGRAPH * DIM; i += 256) {
        int g = i >> 6, d = i & 63;
        float c = (float)gcnt[g];
        emb[g][d] = gsum[i] / fmaxf(c, 1.0f);
    }
    for (int i = tid; i < NGRAPH * GATTR; i += 256) {
        int g = i >> 2, d = i & 3;
        emb[g][DIM + d] = gattr[i];
    }
    __syncthreads();
    for (int t = tid; t < NGRAPH * 32; t += 256) {
        int g = t >> 5, j = t & 31;
        float a = b1[j];
        for (int k = 0; k < DIM + GATTR; ++k) a += emb[g][k] * W1[k * 32 + j];
        hid[g][j] = fmaxf(a, 0.f);
    }
    __syncthreads();
    {
        int g = tid >> 1, o = tid & 1;
        float a = b2[o];
        for (int k = 0; k < 32; ++k) a += hid[g][k] * W2[k * 2 + o];
        out[g * 2 + o] = a;
    }
}

extern "C" void kernel_launch(void* const* d_in, const int* in_sizes, int n_in,
                              void* d_out, int out_size, void* d_ws, size_t ws_size,
                              hipStream_t stream) {
    const float* x = (const float*)d_in[0];
    const int* ei = (const int*)d_in[1];
    const int* batch = (const int*)d_in[2];
    const float* gattr = (const float*)d_in[3];
    const int N = in_sizes[0] / DIM;
    const int E = in_sizes[1] / 2;
    const int* src = ei;
    const int* dst = ei + E;

    const float *Wl[3], *bl[3], *Wr[3], *bg[3], *bb[3], *bm[3], *bv[3];
    for (int l = 0; l < 3; ++l) {
        int base = 4 + l * 7;
        Wl[l] = (const float*)d_in[base + 0];
        bl[l] = (const float*)d_in[base + 1];
        Wr[l] = (const float*)d_in[base + 2];
        bg[l] = (const float*)d_in[base + 3];
        bb[l] = (const float*)d_in[base + 4];
        bm[l] = (const float*)d_in[base + 5];
        bv[l] = (const float*)d_in[base + 6];
    }
    const float* W1 = (const float*)d_in[25];
    const float* b1 = (const float*)d_in[26];
    const float* W2 = (const float*)d_in[27];
    const float* b2 = (const float*)d_in[28];

    char* ws = (char*)d_ws;
    size_t off = 0;
    auto alloc = [&](size_t bytes) -> char* {
        char* p = ws + off;
        off += (bytes + 255) & ~(size_t)255;
        return p;
    };
    int* cnt = (int*)alloc((size_t)N * 4);
    int* rowptr = (int*)alloc((size_t)(N + 1) * 4);
    int* wp = (int*)alloc((size_t)N * 4);
    int* col = (int*)alloc((size_t)E * 4);
    float* aggb = (float*)alloc((size_t)N * DIM * 4);
    float* h0 = (float*)alloc((size_t)N * DIM * 4);
    float* h1 = (float*)alloc((size_t)N * DIM * 4);
    float* gsum = (float*)alloc((size_t)NGRAPH * DIM * 4);
    int* gcnt = (int*)alloc((size_t)NGRAPH * 4);
    int* partials = (int*)alloc(1024 * 4);
    (void)ws_size;

    hipMemsetAsync(cnt, 0, (size_t)N * 4, stream);
    hipMemsetAsync(gsum, 0, (size_t)NGRAPH * DIM * 4, stream);
    hipMemsetAsync(gcnt, 0, (size_t)NGRAPH * 4, stream);

    const int tpb = 256;
    const int nscan = (N + SCAN_CHUNK - 1) / SCAN_CHUNK;
    const int nbE = (E + tpb - 1) / tpb;
    k_count<<<nbE, tpb, 0, stream>>>(dst, cnt, E);
    k_scan1<<<nscan, tpb, 0, stream>>>(cnt, rowptr, partials, N);
    k_scan2<<<1, tpb, 0, stream>>>(partials, nscan);
    k_scan3<<<nscan, tpb, 0, stream>>>(rowptr, wp, partials, N, E);
    {
        int per = (N + NPASS - 1) / NPASS;
        for (int p = 0; p < NPASS; ++p) {
            int lo = p * per;
            int hi = min(lo + per, N);
            if (lo >= hi) break;
            k_scatter_pass<<<nbE, tpb, 0, stream>>>(src, dst, wp, col, E, lo, hi);
        }
    }

    const float* hin = x;
    float* houts[3] = {h0, h1, h0};
    for (int l = 0; l < 3; ++l) {
        k_agg<<<(N * 64 + tpb - 1) / tpb, tpb, 0, stream>>>(hin, rowptr, col, aggb, N);
        k_xform<<<(N + 63) / 64, 256, 0, stream>>>(aggb, hin, Wl[l], bl[l], Wr[l],
                                                   bg[l], bb[l], bm[l], bv[l], houts[l], N);
        hin = houts[l];
    }

    k_pool<<<256, tpb, 0, stream>>>(hin, batch, gsum, gcnt, N);
    k_mlp<<<1, tpb, 0, stream>>>(gsum, gcnt, gattr, W1, b1, W2, b2, (float*)d_out);
}

// Round 8
// 578.967 us; speedup vs baseline: 1.3985x; 1.1056x over previous
//
#include <hip/hip_runtime.h>

#define DIM 64
#define NGRAPH 128
#define GATTR 4
#define BN_EPS 1e-5f
#define SCAN_CHUNK 4096  // 256 threads x 16 elems
#define NPASS 8          // dst-range passes for scatter write locality
#define XS 17            // padded A/H row stride in float4 units (68 floats)

// ---------------- CSR build ----------------

__global__ __launch_bounds__(256) void k_count(const int* __restrict__ dst,
                                               int* __restrict__ cnt, int E) {
    int e = blockIdx.x * blockDim.x + threadIdx.x;
    if (e < E) atomicAdd(&cnt[dst[e]], 1);
}

// Stage 1: per-block local exclusive scan (4096 elems) + block total
__global__ __launch_bounds__(256) void k_scan1(const int* __restrict__ cnt,
                                               int* __restrict__ rowptr,
                                               int* __restrict__ partials, int n) {
    __shared__ int ws[256];
    int tid = threadIdx.x;
    int base = blockIdx.x * SCAN_CHUNK + tid * 16;
    int v[16];
    int s = 0;
#pragma unroll
    for (int i = 0; i < 16; ++i) {
        int idx = base + i;
        v[i] = (idx < n) ? cnt[idx] : 0;
        s += v[i];
    }
    ws[tid] = s;
    __syncthreads();
    for (int off = 1; off < 256; off <<= 1) {
        int t = (tid >= off) ? ws[tid - off] : 0;
        __syncthreads();
        ws[tid] += t;
        __syncthreads();
    }
    int excl = (tid == 0) ? 0 : ws[tid - 1];
    if (tid == 255) partials[blockIdx.x] = ws[255];
#pragma unroll
    for (int i = 0; i < 16; ++i) {
        int idx = base + i;
        if (idx < n) rowptr[idx] = excl;
        excl += v[i];
    }
}

// Stage 2: exclusive scan of block totals (nb <= 256)
__global__ __launch_bounds__(256) void k_scan2(int* __restrict__ partials, int nb) {
    __shared__ int ws[256];
    int tid = threadIdx.x;
    int orig = (tid < nb) ? partials[tid] : 0;
    ws[tid] = orig;
    __syncthreads();
    for (int off = 1; off < 256; off <<= 1) {
        int t = (tid >= off) ? ws[tid - off] : 0;
        __syncthreads();
        ws[tid] += t;
        __syncthreads();
    }
    if (tid < nb) partials[tid] = ws[tid] - orig;  // exclusive
}

// Stage 3: add block offsets, fan out to rowptr and wp
__global__ __launch_bounds__(256) void k_scan3(int* __restrict__ rowptr,
                                               int* __restrict__ wp,
                                               const int* __restrict__ partials,
                                               int n, int E) {
    int base = blockIdx.x * SCAN_CHUNK;
    int off = partials[blockIdx.x];
    for (int i = threadIdx.x; i < SCAN_CHUNK; i += 256) {
        int idx = base + i;
        if (idx < n) {
            int v = rowptr[idx] + off;
            rowptr[idx] = v;
            wp[idx] = v;
        }
    }
    if (blockIdx.x == 0 && threadIdx.x == 0) rowptr[n] = E;
}

// Scatter restricted to dst in [lo, hi): col writes land in a ~640KB window
// per pass -> L2-resident, lines fill before writeback.
__global__ __launch_bounds__(256) void k_scatter_pass(const int* __restrict__ src,
                                                      const int* __restrict__ dst,
                                                      int* __restrict__ wp,
                                                      int* __restrict__ col,
                                                      int E, int lo, int hi) {
    int e = blockIdx.x * blockDim.x + threadIdx.x;
    if (e >= E) return;
    int d = dst[e];
    if (d < lo || d >= hi) return;
    int p = atomicAdd(&wp[d], 1);
    col[p] = src[e];
}

// ---------------- mean aggregation ----------------
// One wave per node. lane = (g, p): g = edge slot (0..3), p = dim quad (0..15).

__global__ __launch_bounds__(256) void k_agg(const float* __restrict__ h,
                                             const int* __restrict__ row_ptr,
                                             const int* __restrict__ col,
                                             float* __restrict__ agg, int n) {
    int wid = (blockIdx.x * blockDim.x + threadIdx.x) >> 6;
    if (wid >= n) return;
    int lane = threadIdx.x & 63;
    int g = lane >> 4;   // edge slot
    int p = lane & 15;   // dim quad: dims 4p..4p+3
    int beg = row_ptr[wid], end = row_ptr[wid + 1];

    float ax = 0.f, ay = 0.f, az = 0.f, aw = 0.f;
    float bx = 0.f, by = 0.f, bz = 0.f, bw = 0.f;
    int j = beg + g;
    for (; j + 4 < end; j += 8) {
        int s0 = col[j];
        int s1 = col[j + 4];
        float4 v0 = ((const float4*)(h + (size_t)s0 * DIM))[p];
        float4 v1 = ((const float4*)(h + (size_t)s1 * DIM))[p];
        ax += v0.x; ay += v0.y; az += v0.z; aw += v0.w;
        bx += v1.x; by += v1.y; bz += v1.z; bw += v1.w;
    }
    if (j < end) {
        int s0 = col[j];
        float4 v0 = ((const float4*)(h + (size_t)s0 * DIM))[p];
        ax += v0.x; ay += v0.y; az += v0.z; aw += v0.w;
    }
    ax += bx; ay += by; az += bz; aw += bw;

#pragma unroll
    for (int m = 16; m <= 32; m <<= 1) {
        ax += __shfl_xor(ax, m, 64);
        ay += __shfl_xor(ay, m, 64);
        az += __shfl_xor(az, m, 64);
        aw += __shfl_xor(aw, m, 64);
    }

    if (g == 0) {
        float c = (float)(end - beg);
        float inv = 1.0f / fmaxf(c, 1.0f);
        float4 r;
        r.x = ax * inv; r.y = ay * inv; r.z = az * inv; r.w = aw * inv;
        ((float4*)(agg + (size_t)wid * DIM))[p] = r;
    }
}

// ---------------- fused linear (agg@Wl + bl + h@Wr) + BN(eval) + ReLU ----------------
// 64-node tile, 256 threads as 16 nq x 16 dq; each thread owns a 4-node x 4-dim
// register tile. Per k-group of 4: 16 ds_read_b128 for 128 FMAs (vs 34 before).
// A/H rows padded to 68 floats so the 4 nq addresses are <=2-way per bank (free).

__global__ __launch_bounds__(256) void k_xform(const float* __restrict__ agg,
                                               const float* __restrict__ h,
                                               const float* __restrict__ Wl,
                                               const float* __restrict__ bl,
                                               const float* __restrict__ Wr,
                                               const float* __restrict__ bng,
                                               const float* __restrict__ bnb,
                                               const float* __restrict__ bnm,
                                               const float* __restrict__ bnv,
                                               float* __restrict__ out, int n) {
    __shared__ float4 sWl[64 * 16];
    __shared__ float4 sWr[64 * 16];
    __shared__ float4 sA[64 * XS];
    __shared__ float4 sH[64 * XS];
    int tid = threadIdx.x;
    int base = blockIdx.x * 64;
    int rows = min(64, n - base);

    const float4* Wl4 = (const float4*)Wl;
    const float4* Wr4 = (const float4*)Wr;
    const float4* A4 = (const float4*)(agg + (size_t)base * DIM);
    const float4* H4 = (const float4*)(h + (size_t)base * DIM);
    for (int i = tid; i < 1024; i += 256) {
        sWl[i] = Wl4[i];
        sWr[i] = Wr4[i];
        int row = i >> 4, c = i & 15;
        float4 va = {0.f, 0.f, 0.f, 0.f}, vh = {0.f, 0.f, 0.f, 0.f};
        if (row < rows) { va = A4[i]; vh = H4[i]; }
        sA[row * XS + c] = va;
        sH[row * XS + c] = vh;
    }
    __syncthreads();

    int dq = tid & 15;   // dim quad: dims 4dq..4dq+3
    int nq = tid >> 4;   // node quad: nodes 4nq..4nq+3
    float4 acc0 = {0.f, 0.f, 0.f, 0.f};
    float4 acc1 = {0.f, 0.f, 0.f, 0.f};
    float4 acc2 = {0.f, 0.f, 0.f, 0.f};
    float4 acc3 = {0.f, 0.f, 0.f, 0.f};

    int arow = nq * 4 * XS;
#pragma unroll 4
    for (int kg = 0; kg < 16; ++kg) {
        float4 wl0 = sWl[(kg * 4 + 0) * 16 + dq];
        float4 wl1 = sWl[(kg * 4 + 1) * 16 + dq];
        float4 wl2 = sWl[(kg * 4 + 2) * 16 + dq];
        float4 wl3 = sWl[(kg * 4 + 3) * 16 + dq];
        float4 wr0 = sWr[(kg * 4 + 0) * 16 + dq];
        float4 wr1 = sWr[(kg * 4 + 1) * 16 + dq];
        float4 wr2 = sWr[(kg * 4 + 2) * 16 + dq];
        float4 wr3 = sWr[(kg * 4 + 3) * 16 + dq];
        float4 a0 = sA[arow + 0 * XS + kg];
        float4 a1 = sA[arow + 1 * XS + kg];
        float4 a2 = sA[arow + 2 * XS + kg];
        float4 a3 = sA[arow + 3 * XS + kg];
        float4 h0 = sH[arow + 0 * XS + kg];
        float4 h1 = sH[arow + 1 * XS + kg];
        float4 h2 = sH[arow + 2 * XS + kg];
        float4 h3 = sH[arow + 3 * XS + kg];
#define ACC1(AC, AV, HV)                                                        \
        AC.x += AV.x * wl0.x + AV.y * wl1.x + AV.z * wl2.x + AV.w * wl3.x       \
              + HV.x * wr0.x + HV.y * wr1.x + HV.z * wr2.x + HV.w * wr3.x;      \
        AC.y += AV.x * wl0.y + AV.y * wl1.y + AV.z * wl2.y + AV.w * wl3.y       \
              + HV.x * wr0.y + HV.y * wr1.y + HV.z * wr2.y + HV.w * wr3.y;      \
        AC.z += AV.x * wl0.z + AV.y * wl1.z + AV.z * wl2.z + AV.w * wl3.z       \
              + HV.x * wr0.z + HV.y * wr1.z + HV.z * wr2.z + HV.w * wr3.z;      \
        AC.w += AV.x * wl0.w + AV.y * wl1.w + AV.z * wl2.w + AV.w * wl3.w       \
              + HV.x * wr0.w + HV.y * wr1.w + HV.z * wr2.w + HV.w * wr3.w;
        ACC1(acc0, a0, h0)
        ACC1(acc1, a1, h1)
        ACC1(acc2, a2, h2)
        ACC1(acc3, a3, h3)
#undef ACC1
    }

    float4 g4 = ((const float4*)bng)[dq];
    float4 v4 = ((const float4*)bnv)[dq];
    float4 be4 = ((const float4*)bnb)[dq];
    float4 rm4 = ((const float4*)bnm)[dq];
    float4 bi4 = ((const float4*)bl)[dq];
    float4 sc;
    sc.x = g4.x / sqrtf(v4.x + BN_EPS);
    sc.y = g4.y / sqrtf(v4.y + BN_EPS);
    sc.z = g4.z / sqrtf(v4.z + BN_EPS);
    sc.w = g4.w / sqrtf(v4.w + BN_EPS);

    float4* accp[4] = {&acc0, &acc1, &acc2, &acc3};
#pragma unroll
    for (int i = 0; i < 4; ++i) {
        int node = base + nq * 4 + i;
        if (node < n) {
            float4 a = *accp[i];
            float4 r;
            r.x = fmaxf((a.x + bi4.x - rm4.x) * sc.x + be4.x, 0.f);
            r.y = fmaxf((a.y + bi4.y - rm4.y) * sc.y + be4.y, 0.f);
            r.z = fmaxf((a.z + bi4.z - rm4.z) * sc.z + be4.z, 0.f);
            r.w = fmaxf((a.w + bi4.w - rm4.w) * sc.w + be4.w, 0.f);
            ((float4*)(out + (size_t)node * DIM))[dq] = r;
        }
    }
}

// ---------------- global mean pool (batch sorted) ----------------

__global__ __launch_bounds__(256) void k_pool(const float* __restrict__ h,
                                              const int* __restrict__ batch,
                                              float* __restrict__ gsum,
                                              int* __restrict__ gcnt, int n) {
    int nw = gridDim.x * 4;
    int w = blockIdx.x * 4 + (threadIdx.x >> 6);
    int lane = threadIdx.x & 63;
    int chunk = (n + nw - 1) / nw;
    int s = w * chunk, e = min(s + chunk, n);
    if (s >= e) return;
    int cur = batch[s];
    float acc = 0.f;
    int cnt = 0;
    for (int i = s; i < e; ++i) {
        int g = batch[i];
        if (g != cur) {
            atomicAdd(&gsum[cur * DIM + lane], acc);
            if (lane == 0) atomicAdd(&gcnt[cur], cnt);
            acc = 0.f; cnt = 0; cur = g;
        }
        acc += h[(size_t)i * DIM + lane];
        ++cnt;
    }
    atomicAdd(&gsum[cur * DIM + lane], acc);
    if (lane == 0) atomicAdd(&gcnt[cur], cnt);
}

// ---------------- classifier head ----------------

__global__ __launch_bounds__(256) void k_mlp(const float* __restrict__ gsum,
                                             const int* __restrict__ gcnt,
                                             const float* __restrict__ gattr,
                                             const float* __restrict__ W1,
                                             const float* __restrict__ b1,
                                             const float* __restrict__ W2,
                                             const float* __restrict__ b2,
                                             float* __restrict__ out) {
    __shared__ float emb[NGRAPH][DIM + GATTR];
    __shared__ float hid[NGRAPH][32];
    int tid = threadIdx.x;
    for (int i = tid; i < NGRAPH * DIM; i += 256) {
        int g = i >> 6, d = i & 63;
        float c = (float)gcnt[g];
        emb[g][d] = gsum[i] / fmaxf(c, 1.0f);
    }
    for (int i = tid; i < NGRAPH * GATTR; i += 256) {
        int g = i >> 2, d = i & 3;
        emb[g][DIM + d] = gattr[i];
    }
    __syncthreads();
    for (int t = tid; t < NGRAPH * 32; t += 256) {
        int g = t >> 5, j = t & 31;
        float a = b1[j];
        for (int k = 0; k < DIM + GATTR; ++k) a += emb[g][k] * W1[k * 32 + j];
        hid[g][j] = fmaxf(a, 0.f);
    }
    __syncthreads();
    {
        int g = tid >> 1, o = tid & 1;
        float a = b2[o];
        for (int k = 0; k < 32; ++k) a += hid[g][k] * W2[k * 2 + o];
        out[g * 2 + o] = a;
    }
}

extern "C" void kernel_launch(void* const* d_in, const int* in_sizes, int n_in,
                              void* d_out, int out_size, void* d_ws, size_t ws_size,
                              hipStream_t stream) {
    const float* x = (const float*)d_in[0];
    const int* ei = (const int*)d_in[1];
    const int* batch = (const int*)d_in[2];
    const float* gattr = (const float*)d_in[3];
    const int N = in_sizes[0] / DIM;
    const int E = in_sizes[1] / 2;
    const int* src = ei;
    const int* dst = ei + E;

    const float *Wl[3], *bl[3], *Wr[3], *bg[3], *bb[3], *bm[3], *bv[3];
    for (int l = 0; l < 3; ++l) {
        int base = 4 + l * 7;
        Wl[l] = (const float*)d_in[base + 0];
        bl[l] = (const float*)d_in[base + 1];
        Wr[l] = (const float*)d_in[base + 2];
        bg[l] = (const float*)d_in[base + 3];
        bb[l] = (const float*)d_in[base + 4];
        bm[l] = (const float*)d_in[base + 5];
        bv[l] = (const float*)d_in[base + 6];
    }
    const float* W1 = (const float*)d_in[25];
    const float* b1 = (const float*)d_in[26];
    const float* W2 = (const float*)d_in[27];
    const float* b2 = (const float*)d_in[28];

    char* ws = (char*)d_ws;
    size_t off = 0;
    auto alloc = [&](size_t bytes) -> char* {
        char* p = ws + off;
        off += (bytes + 255) & ~(size_t)255;
        return p;
    };
    int* cnt = (int*)alloc((size_t)N * 4);
    int* rowptr = (int*)alloc((size_t)(N + 1) * 4);
    int* wp = (int*)alloc((size_t)N * 4);
    int* col = (int*)alloc((size_t)E * 4);
    float* aggb = (float*)alloc((size_t)N * DIM * 4);
    float* h0 = (float*)alloc((size_t)N * DIM * 4);
    float* h1 = (float*)alloc((size_t)N * DIM * 4);
    float* gsum = (float*)alloc((size_t)NGRAPH * DIM * 4);
    int* gcnt = (int*)alloc((size_t)NGRAPH * 4);
    int* partials = (int*)alloc(1024 * 4);
    (void)ws_size;

    hipMemsetAsync(cnt, 0, (size_t)N * 4, stream);
    hipMemsetAsync(gsum, 0, (size_t)NGRAPH * DIM * 4, stream);
    hipMemsetAsync(gcnt, 0, (size_t)NGRAPH * 4, stream);

    const int tpb = 256;
    const int nscan = (N + SCAN_CHUNK - 1) / SCAN_CHUNK;
    const int nbE = (E + tpb - 1) / tpb;
    k_count<<<nbE, tpb, 0, stream>>>(dst, cnt, E);
    k_scan1<<<nscan, tpb, 0, stream>>>(cnt, rowptr, partials, N);
    k_scan2<<<1, tpb, 0, stream>>>(partials, nscan);
    k_scan3<<<nscan, tpb, 0, stream>>>(rowptr, wp, partials, N, E);
    {
        int per = (N + NPASS - 1) / NPASS;
        for (int p = 0; p < NPASS; ++p) {
            int lo = p * per;
            int hi = min(lo + per, N);
            if (lo >= hi) break;
            k_scatter_pass<<<nbE, tpb, 0, stream>>>(src, dst, wp, col, E, lo, hi);
        }
    }

    const float* hin = x;
    float* houts[3] = {h0, h1, h0};
    for (int l = 0; l < 3; ++l) {
        k_agg<<<(N * 64 + tpb - 1) / tpb, tpb, 0, stream>>>(hin, rowptr, col, aggb, N);
        k_xform<<<(N + 63) / 64, 256, 0, stream>>>(aggb, hin, Wl[l], bl[l], Wr[l],
                                                   bg[l], bb[l], bm[l], bv[l], houts[l], N);
        hin = houts[l];
    }

    k_pool<<<256, tpb, 0, stream>>>(hin, batch, gsum, gcnt, N);
    k_mlp<<<1, tpb, 0, stream>>>(gsum, gcnt, gattr, W1, b1, W2, b2, (float*)d_out);
}

// Round 10
// 537.596 us; speedup vs baseline: 1.5061x; 1.0770x over previous
//
#include <hip/hip_runtime.h>
#include <hip/hip_fp16.h>

#define DIM 64
#define NGRAPH 128
#define GATTR 4
#define BN_EPS 1e-5f
#define SCAN_CHUNK 4096  // 256 threads x 16 elems
#define NPASS 4          // dst-range passes for scatter write locality
#define XS 17            // padded A/H row stride in float4 units (68 floats)

// ---------------- workspace zeroing (replaces 3 memsets) ----------------

__global__ __launch_bounds__(256) void k_zero(int* __restrict__ cnt, int n,
                                              float* __restrict__ gsum,
                                              int* __restrict__ gcnt) {
    int stride = gridDim.x * 256;
    for (int i = blockIdx.x * 256 + threadIdx.x; i < n; i += stride) cnt[i] = 0;
    int i0 = blockIdx.x * 256 + threadIdx.x;
    if (i0 < NGRAPH * DIM) gsum[i0] = 0.f;
    if (i0 < NGRAPH) gcnt[i0] = 0;
}

// ---------------- f32 -> fp16 cast for input features ----------------

__global__ __launch_bounds__(256) void k_cast(const float4* __restrict__ x4,
                                              uint2* __restrict__ o, int n4) {
    int stride = gridDim.x * 256;
    for (int i = blockIdx.x * 256 + threadIdx.x; i < n4; i += stride) {
        float4 v = x4[i];
        __half2 a = __float22half2_rn(make_float2(v.x, v.y));
        __half2 b = __float22half2_rn(make_float2(v.z, v.w));
        uint2 u;
        u.x = *(unsigned int*)&a;
        u.y = *(unsigned int*)&b;
        o[i] = u;
    }
}

// ---------------- CSR build ----------------

__global__ __launch_bounds__(256) void k_count(const int* __restrict__ dst,
                                               int* __restrict__ cnt, int E) {
    int e = blockIdx.x * blockDim.x + threadIdx.x;
    if (e < E) atomicAdd(&cnt[dst[e]], 1);
}

// Stage 1: per-block local exclusive scan (4096 elems) + raw block total
__global__ __launch_bounds__(256) void k_scan1(const int* __restrict__ cnt,
                                               int* __restrict__ rowptr,
                                               int* __restrict__ partials, int n) {
    __shared__ int ws[256];
    int tid = threadIdx.x;
    int base = blockIdx.x * SCAN_CHUNK + tid * 16;
    int v[16];
    int s = 0;
#pragma unroll
    for (int i = 0; i < 16; ++i) {
        int idx = base + i;
        v[i] = (idx < n) ? cnt[idx] : 0;
        s += v[i];
    }
    ws[tid] = s;
    __syncthreads();
    for (int off = 1; off < 256; off <<= 1) {
        int t = (tid >= off) ? ws[tid - off] : 0;
        __syncthreads();
        ws[tid] += t;
        __syncthreads();
    }
    int excl = (tid == 0) ? 0 : ws[tid - 1];
    if (tid == 255) partials[blockIdx.x] = ws[255];
#pragma unroll
    for (int i = 0; i < 16; ++i) {
        int idx = base + i;
        if (idx < n) rowptr[idx] = excl;
        excl += v[i];
    }
}

// Stage 2+3 merged: each block inlines the prefix over <=25 raw partials,
// then adds its offset and fans out to rowptr and wp.
__global__ __launch_bounds__(256) void k_scan23(int* __restrict__ rowptr,
                                                int* __restrict__ wp,
                                                const int* __restrict__ partials,
                                                int n, int E) {
    __shared__ int soff;
    if (threadIdx.x == 0) {
        int s = 0;
        for (int j = 0; j < blockIdx.x; ++j) s += partials[j];
        soff = s;
    }
    __syncthreads();
    int off = soff;
    int base = blockIdx.x * SCAN_CHUNK;
    for (int i = threadIdx.x; i < SCAN_CHUNK; i += 256) {
        int idx = base + i;
        if (idx < n) {
            int v = rowptr[idx] + off;
            rowptr[idx] = v;
            wp[idx] = v;
        }
    }
    if (blockIdx.x == 0 && threadIdx.x == 0) rowptr[n] = E;
}

// Scatter restricted to dst in [lo, hi): col writes land in a ~1.25MB window
// per pass -> L2-resident, lines fill before writeback.
__global__ __launch_bounds__(256) void k_scatter_pass(const int* __restrict__ src,
                                                      const int* __restrict__ dst,
                                                      int* __restrict__ wp,
                                                      int* __restrict__ col,
                                                      int E, int lo, int hi) {
    int e = blockIdx.x * blockDim.x + threadIdx.x;
    if (e >= E) return;
    int d = dst[e];
    if (d < lo || d >= hi) return;
    int p = atomicAdd(&wp[d], 1);
    col[p] = src[e];
}

// ---------------- mean aggregation (fp16 features) ----------------
// One wave per node. lane = (g, p): g = edge slot (0..7), p = dim oct (0..7).
// Each lane loads uint4 = 8 halfs -> one instr gathers 8 rows; unroll x2 ->
// 16 independent gathers in flight. Reduce across g via 3 shfl_xor rounds.
// Output agg stays f32 (coalesced, consumed once by k_xform).

__global__ __launch_bounds__(256) void k_agg(const __half* __restrict__ h16,
                                             const int* __restrict__ row_ptr,
                                             const int* __restrict__ col,
                                             float* __restrict__ agg, int n) {
    int wid = (blockIdx.x * blockDim.x + threadIdx.x) >> 6;
    if (wid >= n) return;
    int lane = threadIdx.x & 63;
    int g = lane >> 3;   // edge slot (8)
    int p = lane & 7;    // dim oct: dims 8p..8p+7
    int beg = row_ptr[wid], end = row_ptr[wid + 1];

    float a0 = 0.f, a1 = 0.f, a2 = 0.f, a3 = 0.f;
    float a4 = 0.f, a5 = 0.f, a6 = 0.f, a7 = 0.f;

#define ACCUM(V)                                                          \
    {                                                                     \
        const __half2* q = (const __half2*)&(V);                          \
        float2 f0 = __half22float2(q[0]);                                 \
        float2 f1 = __half22float2(q[1]);                                 \
        float2 f2 = __half22float2(q[2]);                                 \
        float2 f3 = __half22float2(q[3]);                                 \
        a0 += f0.x; a1 += f0.y; a2 += f1.x; a3 += f1.y;                   \
        a4 += f2.x; a5 += f2.y; a6 += f3.x; a7 += f3.y;                   \
    }

    int j = beg + g;
    for (; j + 8 < end; j += 16) {
        int s0 = col[j];
        int s1 = col[j + 8];
        uint4 v0 = ((const uint4*)(h16 + (size_t)s0 * DIM))[p];
        uint4 v1 = ((const uint4*)(h16 + (size_t)s1 * DIM))[p];
        ACCUM(v0)
        ACCUM(v1)
    }
    if (j < end) {
        int s0 = col[j];
        uint4 v0 = ((const uint4*)(h16 + (size_t)s0 * DIM))[p];
        ACCUM(v0)
    }
#undef ACCUM

    // reduce across the 8 edge slots (lanes differing in bits 3,4,5)
#pragma unroll
    for (int m = 8; m <= 32; m <<= 1) {
        a0 += __shfl_xor(a0, m, 64);
        a1 += __shfl_xor(a1, m, 64);
        a2 += __shfl_xor(a2, m, 64);
        a3 += __shfl_xor(a3, m, 64);
        a4 += __shfl_xor(a4, m, 64);
        a5 += __shfl_xor(a5, m, 64);
        a6 += __shfl_xor(a6, m, 64);
        a7 += __shfl_xor(a7, m, 64);
    }

    if (g == 0) {
        float c = (float)(end - beg);
        float inv = 1.0f / fmaxf(c, 1.0f);
        float4* op = (float4*)(agg + (size_t)wid * DIM + p * 8);
        float4 r0, r1;
        r0.x = a0 * inv; r0.y = a1 * inv; r0.z = a2 * inv; r0.w = a3 * inv;
        r1.x = a4 * inv; r1.y = a5 * inv; r1.z = a6 * inv; r1.w = a7 * inv;
        op[0] = r0;
        op[1] = r1;
    }
}

// ---------------- fused linear (agg@Wl + bl + h@Wr) + BN(eval) + ReLU ----------------
// 64-node tile, 256 threads as 16 nq x 16 dq; 4-node x 4-dim register tile each.
// Self-path features read from fp16 h16; output written as fp16.

__global__ __launch_bounds__(256) void k_xform(const float* __restrict__ agg,
                                               const __half* __restrict__ h16,
                                               const float* __restrict__ Wl,
                                               const float* __restrict__ bl,
                                               const float* __restrict__ Wr,
                                               const float* __restrict__ bng,
                                               const float* __restrict__ bnb,
                                               const float* __restrict__ bnm,
                                               const float* __restrict__ bnv,
                                               __half* __restrict__ out16, int n) {
    __shared__ float4 sWl[64 * 16];
    __shared__ float4 sWr[64 * 16];
    __shared__ float4 sA[64 * XS];
    __shared__ float4 sH[64 * XS];
    int tid = threadIdx.x;
    int base = blockIdx.x * 64;
    int rows = min(64, n - base);

    const float4* Wl4 = (const float4*)Wl;
    const float4* Wr4 = (const float4*)Wr;
    const float4* A4 = (const float4*)(agg + (size_t)base * DIM);
    const uint2* H2 = (const uint2*)(h16 + (size_t)base * DIM);  // 8B = 4 halfs
    for (int i = tid; i < 1024; i += 256) {
        sWl[i] = Wl4[i];
        sWr[i] = Wr4[i];
        int row = i >> 4, c = i & 15;
        float4 va = {0.f, 0.f, 0.f, 0.f}, vh = {0.f, 0.f, 0.f, 0.f};
        if (row < rows) {
            va = A4[i];
            uint2 u = H2[i];
            const __half2* q = (const __half2*)&u;
            float2 lo = __half22float2(q[0]);
            float2 hi = __half22float2(q[1]);
            vh.x = lo.x; vh.y = lo.y; vh.z = hi.x; vh.w = hi.y;
        }
        sA[row * XS + c] = va;
        sH[row * XS + c] = vh;
    }
    __syncthreads();

    int dq = tid & 15;   // dim quad: dims 4dq..4dq+3
    int nq = tid >> 4;   // node quad: nodes 4nq..4nq+3
    float4 acc0 = {0.f, 0.f, 0.f, 0.f};
    float4 acc1 = {0.f, 0.f, 0.f, 0.f};
    float4 acc2 = {0.f, 0.f, 0.f, 0.f};
    float4 acc3 = {0.f, 0.f, 0.f, 0.f};

    int arow = nq * 4 * XS;
#pragma unroll 4
    for (int kg = 0; kg < 16; ++kg) {
        float4 wl0 = sWl[(kg * 4 + 0) * 16 + dq];
        float4 wl1 = sWl[(kg * 4 + 1) * 16 + dq];
        float4 wl2 = sWl[(kg * 4 + 2) * 16 + dq];
        float4 wl3 = sWl[(kg * 4 + 3) * 16 + dq];
        float4 wr0 = sWr[(kg * 4 + 0) * 16 + dq];
        float4 wr1 = sWr[(kg * 4 + 1) * 16 + dq];
        float4 wr2 = sWr[(kg * 4 + 2) * 16 + dq];
        float4 wr3 = sWr[(kg * 4 + 3) * 16 + dq];
        float4 a0 = sA[arow + 0 * XS + kg];
        float4 a1 = sA[arow + 1 * XS + kg];
        float4 a2 = sA[arow + 2 * XS + kg];
        float4 a3 = sA[arow + 3 * XS + kg];
        float4 h0 = sH[arow + 0 * XS + kg];
        float4 h1 = sH[arow + 1 * XS + kg];
        float4 h2 = sH[arow + 2 * XS + kg];
        float4 h3 = sH[arow + 3 * XS + kg];
#define ACC1(AC, AV, HV)                                                        \
        AC.x += AV.x * wl0.x + AV.y * wl1.x + AV.z * wl2.x + AV.w * wl3.x       \
              + HV.x * wr0.x + HV.y * wr1.x + HV.z * wr2.x + HV.w * wr3.x;      \
        AC.y += AV.x * wl0.y + AV.y * wl1.y + AV.z * wl2.y + AV.w * wl3.y       \
              + HV.x * wr0.y + HV.y * wr1.y + HV.z * wr2.y + HV.w * wr3.y;      \
        AC.z += AV.x * wl0.z + AV.y * wl1.z + AV.z * wl2.z + AV.w * wl3.z       \
              + HV.x * wr0.z + HV.y * wr1.z + HV.z * wr2.z + HV.w * wr3.z;      \
        AC.w += AV.x * wl0.w + AV.y * wl1.w + AV.z * wl2.w + AV.w * wl3.w       \
              + HV.x * wr0.w + HV.y * wr1.w + HV.z * wr2.w + HV.w * wr3.w;
        ACC1(acc0, a0, h0)
        ACC1(acc1, a1, h1)
        ACC1(acc2, a2, h2)
        ACC1(acc3, a3, h3)
#undef ACC1
    }

    float4 g4 = ((const float4*)bng)[dq];
    float4 v4 = ((const float4*)bnv)[dq];
    float4 be4 = ((const float4*)bnb)[dq];
    float4 rm4 = ((const float4*)bnm)[dq];
    float4 bi4 = ((const float4*)bl)[dq];
    float4 sc;
    sc.x = g4.x / sqrtf(v4.x + BN_EPS);
    sc.y = g4.y / sqrtf(v4.y + BN_EPS);
    sc.z = g4.z / sqrtf(v4.z + BN_EPS);
    sc.w = g4.w / sqrtf(v4.w + BN_EPS);

    float4* accp[4] = {&acc0, &acc1, &acc2, &acc3};
#pragma unroll
    for (int i = 0; i < 4; ++i) {
        int node = base + nq * 4 + i;
        if (node < n) {
            float4 a = *accp[i];
            float4 r;
            r.x = fmaxf((a.x + bi4.x - rm4.x) * sc.x + be4.x, 0.f);
            r.y = fmaxf((a.y + bi4.y - rm4.y) * sc.y + be4.y, 0.f);
            r.z = fmaxf((a.z + bi4.z - rm4.z) * sc.z + be4.z, 0.f);
            r.w = fmaxf((a.w + bi4.w - rm4.w) * sc.w + be4.w, 0.f);
            __half2 o01 = __float22half2_rn(make_float2(r.x, r.y));
            __half2 o23 = __float22half2_rn(make_float2(r.z, r.w));
            uint2 u;
            u.x = *(unsigned int*)&o01;
            u.y = *(unsigned int*)&o23;
            ((uint2*)(out16 + (size_t)node * DIM))[dq] = u;
        }
    }
}

// ---------------- global mean pool (batch sorted, fp16 features) ----------------

__global__ __launch_bounds__(256) void k_pool(const __half* __restrict__ h16,
                                              const int* __restrict__ batch,
                                              float* __restrict__ gsum,
                                              int* __restrict__ gcnt, int n) {
    int nw = gridDim.x * 4;
    int w = blockIdx.x * 4 + (threadIdx.x >> 6);
    int lane = threadIdx.x & 63;
    int chunk = (n + nw - 1) / nw;
    int s = w * chunk, e = min(s + chunk, n);
    if (s >= e) return;
    int cur = batch[s];
    float acc = 0.f;
    int cnt = 0;
    for (int i = s; i < e; ++i) {
        int g = batch[i];
        if (g != cur) {
            atomicAdd(&gsum[cur * DIM + lane], acc);
            if (lane == 0) atomicAdd(&gcnt[cur], cnt);
            acc = 0.f; cnt = 0; cur = g;
        }
        acc += __half2float(h16[(size_t)i * DIM + lane]);
        ++cnt;
    }
    atomicAdd(&gsum[cur * DIM + lane], acc);
    if (lane == 0) atomicAdd(&gcnt[cur], cnt);
}

// ---------------- classifier head ----------------

__global__ __launch_bounds__(256) void k_mlp(const float* __restrict__ gsum,
                                             const int* __restrict__ gcnt,
                                             const float* __restrict__ gattr,
                                             const float* __restrict__ W1,
                                             const float* __restrict__ b1,
                                             const float* __restrict__ W2,
                                             const float* __restrict__ b2,
                                             float* __restrict__ out) {
    __shared__ float emb[NGRAPH][DIM + GATTR];
    __shared__ float hid[NGRAPH][32];
    int tid = threadIdx.x;
    for (int i = tid; i < NGRAPH * DIM; i += 256) {
        int g = i >> 6, d = i & 63;
        float c = (float)gcnt[g];
        emb[g][d] = gsum[i] / fmaxf(c, 1.0f);
    }
    for (int i = tid; i < NGRAPH * GATTR; i += 256) {
        int g = i >> 2, d = i & 3;
        emb[g][DIM + d] = gattr[i];
    }
    __syncthreads();
    for (int t = tid; t < NGRAPH * 32; t += 256) {
        int g = t >> 5, j = t & 31;
        float a = b1[j];
        for (int k = 0; k < DIM + GATTR; ++k) a += emb[g][k] * W1[k * 32 + j];
        hid[g][j] = fmaxf(a, 0.f);
    }
    __syncthreads();
    {
        int g = tid >> 1, o = tid & 1;
        float a = b2[o];
        for (int k = 0; k < 32; ++k) a += hid[g][k] * W2[k * 2 + o];
        out[g * 2 + o] = a;
    }
}

extern "C" void kernel_launch(void* const* d_in, const int* in_sizes, int n_in,
                              void* d_out, int out_size, void* d_ws, size_t ws_size,
                              hipStream_t stream) {
    const float* x = (const float*)d_in[0];
    const int* ei = (const int*)d_in[1];
    const int* batch = (const int*)d_in[2];
    const float* gattr = (const float*)d_in[3];
    const int N = in_sizes[0] / DIM;
    const int E = in_sizes[1] / 2;
    const int* src = ei;
    const int* dst = ei + E;

    const float *Wl[3], *bl[3], *Wr[3], *bg[3], *bb[3], *bm[3], *bv[3];
    for (int l = 0; l < 3; ++l) {
        int base = 4 + l * 7;
        Wl[l] = (const float*)d_in[base + 0];
        bl[l] = (const float*)d_in[base + 1];
        Wr[l] = (const float*)d_in[base + 2];
        bg[l] = (const float*)d_in[base + 3];
        bb[l] = (const float*)d_in[base + 4];
        bm[l] = (const float*)d_in[base + 5];
        bv[l] = (const float*)d_in[base + 6];
    }
    const float* W1 = (const float*)d_in[25];
    const float* b1 = (const float*)d_in[26];
    const float* W2 = (const float*)d_in[27];
    const float* b2 = (const float*)d_in[28];

    char* ws = (char*)d_ws;
    size_t off = 0;
    auto alloc = [&](size_t bytes) -> char* {
        char* p = ws + off;
        off += (bytes + 255) & ~(size_t)255;
        return p;
    };
    int* cnt = (int*)alloc((size_t)N * 4);
    int* rowptr = (int*)alloc((size_t)(N + 1) * 4);
    int* wp = (int*)alloc((size_t)N * 4);
    int* col = (int*)alloc((size_t)E * 4);
    float* aggb = (float*)alloc((size_t)N * DIM * 4);
    __half* x16 = (__half*)alloc((size_t)N * DIM * 2);
    __half* h16a = (__half*)alloc((size_t)N * DIM * 2);
    __half* h16b = (__half*)alloc((size_t)N * DIM * 2);
    float* gsum = (float*)alloc((size_t)NGRAPH * DIM * 4);
    int* gcnt = (int*)alloc((size_t)NGRAPH * 4);
    int* partials = (int*)alloc(1024 * 4);
    (void)ws_size;

    const int tpb = 256;
    const int nscan = (N + SCAN_CHUNK - 1) / SCAN_CHUNK;
    const int nbE = (E + tpb - 1) / tpb;

    k_zero<<<512, tpb, 0, stream>>>(cnt, N, gsum, gcnt);
    k_cast<<<1024, tpb, 0, stream>>>((const float4*)x, (uint2*)x16, N * DIM / 4);
    k_count<<<nbE, tpb, 0, stream>>>(dst, cnt, E);
    k_scan1<<<nscan, tpb, 0, stream>>>(cnt, rowptr, partials, N);
    k_scan23<<<nscan, tpb, 0, stream>>>(rowptr, wp, partials, N, E);
    {
        int per = (N + NPASS - 1) / NPASS;
        for (int p = 0; p < NPASS; ++p) {
            int lo = p * per;
            int hi = min(lo + per, N);
            if (lo >= hi) break;
            k_scatter_pass<<<nbE, tpb, 0, stream>>>(src, dst, wp, col, E, lo, hi);
        }
    }

    const __half* hin = x16;
    __half* houts[3] = {h16a, h16b, h16a};
    for (int l = 0; l < 3; ++l) {
        k_agg<<<(N * 64 + tpb - 1) / tpb, tpb, 0, stream>>>(hin, rowptr, col, aggb, N);
        k_xform<<<(N + 63) / 64, 256, 0, stream>>>(aggb, hin, Wl[l], bl[l], Wr[l],
                                                   bg[l], bb[l], bm[l], bv[l], houts[l], N);
        hin = houts[l];
    }

    k_pool<<<256, tpb, 0, stream>>>(hin, batch, gsum, gcnt, N);
    k_mlp<<<1, tpb, 0, stream>>>(gsum, gcnt, gattr, W1, b1, W2, b2, (float*)d_out);
}

// Round 13
// 454.687 us; speedup vs baseline: 1.7808x; 1.1823x over previous
//
#include <hip/hip_runtime.h>
#include <hip/hip_fp16.h>

#define DIM 64
#define NGRAPH 128
#define GATTR 4
#define BN_EPS 1e-5f
#define SCAN_CHUNK 4096   // 256 threads x 16 elems (generic scan)
#define SCHUNK 4096       // edges per binning block
#define BUCKET_SHIFT 7
#define BUCKET 128        // nodes per bucket; nbuck = ceil(N/128)
#define XS 17             // padded A/H row stride in float4 units (68 floats)

// ---------------- small zero (gsum/gcnt only) ----------------

__global__ __launch_bounds__(256) void k_zero(float* __restrict__ gsum,
                                              int* __restrict__ gcnt) {
    int i0 = blockIdx.x * 256 + threadIdx.x;
    if (i0 < NGRAPH * DIM) gsum[i0] = 0.f;
    if (i0 < NGRAPH) gcnt[i0] = 0;
}

// ---------------- f32 -> fp16 cast for input features ----------------

__global__ __launch_bounds__(256) void k_cast(const float4* __restrict__ x4,
                                              uint2* __restrict__ o, int n4) {
    int stride = gridDim.x * 256;
    for (int i = blockIdx.x * 256 + threadIdx.x; i < n4; i += stride) {
        float4 v = x4[i];
        __half2 a = __float22half2_rn(make_float2(v.x, v.y));
        __half2 b = __float22half2_rn(make_float2(v.z, v.w));
        uint2 u;
        u.x = *(unsigned int*)&a;
        u.y = *(unsigned int*)&b;
        o[i] = u;
    }
}

// ---------------- CSR build: deterministic rank-and-place (no global atomics) ----

// Per-block LDS histogram of buckets; plain stores (every entry written).
__global__ __launch_bounds__(256) void k_bhist(const int* __restrict__ dst,
                                               int* __restrict__ hist,
                                               int E, int nb, int nbuck) {
    __shared__ int lb[1024];
    int tid = threadIdx.x, blk = blockIdx.x;
    int base = blk * SCHUNK;
    int cnt = min(SCHUNK, E - base);
    for (int i = tid; i < nbuck; i += 256) lb[i] = 0;
    __syncthreads();
    for (int i = tid; i < cnt; i += 256)
        atomicAdd(&lb[dst[base + i] >> BUCKET_SHIFT], 1);
    __syncthreads();
    for (int b = tid; b < nbuck; b += 256) hist[b * nb + blk] = lb[b];
}

// Generic multi-block exclusive scan, stage 1 (in-place safe: in may == out)
__global__ __launch_bounds__(256) void k_gscan1(const int* __restrict__ in,
                                                int* __restrict__ out,
                                                int* __restrict__ partials, int n) {
    __shared__ int ws[256];
    int tid = threadIdx.x;
    int base = blockIdx.x * SCAN_CHUNK + tid * 16;
    int v[16];
    int s = 0;
#pragma unroll
    for (int i = 0; i < 16; ++i) {
        int idx = base + i;
        v[i] = (idx < n) ? in[idx] : 0;
        s += v[i];
    }
    ws[tid] = s;
    __syncthreads();
    for (int off = 1; off < 256; off <<= 1) {
        int t = (tid >= off) ? ws[tid - off] : 0;
        __syncthreads();
        ws[tid] += t;
        __syncthreads();
    }
    int excl = (tid == 0) ? 0 : ws[tid - 1];
    if (tid == 255) partials[blockIdx.x] = ws[255];
#pragma unroll
    for (int i = 0; i < 16; ++i) {
        int idx = base + i;
        if (idx < n) out[idx] = excl;
        excl += v[i];
    }
}

// Generic stage 2+3: inline prefix over block partials, add offset in place.
__global__ __launch_bounds__(256) void k_gscan23(int* __restrict__ data,
                                                 const int* __restrict__ partials,
                                                 int n) {
    __shared__ int soff;
    if (threadIdx.x == 0) {
        int s = 0;
        for (int j = 0; j < blockIdx.x; ++j) s += partials[j];
        soff = s;
    }
    __syncthreads();
    int off = soff;
    int base = blockIdx.x * SCAN_CHUNK;
    for (int i = threadIdx.x; i < SCAN_CHUNK; i += 256) {
        int idx = base + i;
        if (idx < n) data[idx] += off;
    }
}

// Deterministic binning: LDS-sort the block's edges by bucket, then write each
// pair to its exact precomputed global slot. No global atomics anywhere.
__global__ __launch_bounds__(256) void k_sbin(const int* __restrict__ src,
                                              const int* __restrict__ dst,
                                              const int* __restrict__ hist,
                                              int2* __restrict__ pairs,
                                              int E, int nb, int nbuck) {
    __shared__ int lhist[1024];
    __shared__ int lofs[1024];   // fixed local starts
    __shared__ int lcur[1024];   // cursors
    __shared__ int lgb[1024];    // global segment base for (bucket, this block)
    __shared__ int ws[256];
    __shared__ int2 stage[SCHUNK];  // 32 KiB
    int tid = threadIdx.x, blk = blockIdx.x;
    int base = blk * SCHUNK;
    int cnt = min(SCHUNK, E - base);

    for (int i = tid; i < nbuck; i += 256) lhist[i] = 0;
    __syncthreads();

    int2 mine[16];
    int nmine = 0;
    for (int i = tid; i < cnt; i += 256) {
        int s = src[base + i];
        int d = dst[base + i];
        mine[nmine++] = make_int2(s, d);
        atomicAdd(&lhist[d >> BUCKET_SHIFT], 1);
    }
    __syncthreads();

    // exclusive scan of lhist[0..nbuck), 4 bins per thread
    {
        int b0 = tid * 4;
        int v0 = (b0 + 0 < nbuck) ? lhist[b0 + 0] : 0;
        int v1 = (b0 + 1 < nbuck) ? lhist[b0 + 1] : 0;
        int v2 = (b0 + 2 < nbuck) ? lhist[b0 + 2] : 0;
        int v3 = (b0 + 3 < nbuck) ? lhist[b0 + 3] : 0;
        int s = v0 + v1 + v2 + v3;
        ws[tid] = s;
        __syncthreads();
        for (int off = 1; off < 256; off <<= 1) {
            int t = (tid >= off) ? ws[tid - off] : 0;
            __syncthreads();
            ws[tid] += t;
            __syncthreads();
        }
        int excl = (tid == 0) ? 0 : ws[tid - 1];
        if (b0 + 0 < nbuck) lofs[b0 + 0] = excl;
        excl += v0;
        if (b0 + 1 < nbuck) lofs[b0 + 1] = excl;
        excl += v1;
        if (b0 + 2 < nbuck) lofs[b0 + 2] = excl;
        excl += v2;
        if (b0 + 3 < nbuck) lofs[b0 + 3] = excl;
    }
    __syncthreads();
    for (int b = tid; b < nbuck; b += 256) {
        lcur[b] = lofs[b];
        lgb[b] = hist[b * nb + blk];
    }
    __syncthreads();

    for (int j = 0; j < nmine; ++j) {
        int b = mine[j].y >> BUCKET_SHIFT;
        int pos = atomicAdd(&lcur[b], 1);
        stage[pos] = mine[j];
    }
    __syncthreads();

    for (int i = tid; i < cnt; i += 256) {
        int2 pr = stage[i];
        int b = pr.y >> BUCKET_SHIFT;
        pairs[lgb[b] + (i - lofs[b])] = pr;
    }
}

// Per-bucket counting sort -> col + rowptr (one block per bucket; LDS only).
__global__ __launch_bounds__(256) void k_bsort(const int2* __restrict__ pairs,
                                               const int* __restrict__ hist,
                                               int* __restrict__ rowptr,
                                               int* __restrict__ col,
                                               int n, int nb, int nbuck, int E) {
    __shared__ int lcnt[BUCKET];
    __shared__ int lofs[BUCKET];
    int b = blockIdx.x;
    int tid = threadIdx.x;
    int cbase = hist[b * nb];
    int nxt = (b + 1 < nbuck) ? hist[(b + 1) * nb] : E;
    int ecnt = nxt - cbase;
    int node0 = b << BUCKET_SHIFT;
    int nn = min(BUCKET, n - node0);
    if (tid < BUCKET) lcnt[tid] = 0;
    __syncthreads();
    for (int i = tid; i < ecnt; i += 256)
        atomicAdd(&lcnt[pairs[cbase + i].y - node0], 1);
    __syncthreads();
    int v = (tid < BUCKET) ? lcnt[tid] : 0;
    if (tid < BUCKET) lofs[tid] = v;
    __syncthreads();
    for (int off = 1; off < BUCKET; off <<= 1) {
        int t = (tid < BUCKET && tid >= off) ? lofs[tid - off] : 0;
        __syncthreads();
        if (tid < BUCKET) lofs[tid] += t;
        __syncthreads();
    }
    int excl = (tid < BUCKET) ? (lofs[tid] - v) : 0;
    __syncthreads();
    if (tid < BUCKET) lofs[tid] = excl;       // write cursors
    if (tid < nn) rowptr[node0 + tid] = cbase + excl;
    __syncthreads();
    for (int i = tid; i < ecnt; i += 256) {
        int2 pr = pairs[cbase + i];
        int p = cbase + atomicAdd(&lofs[pr.y - node0], 1);
        col[p] = pr.x;
    }
    if (b == 0 && tid == 0) rowptr[n] = E;
}

// ---------------- mean aggregation (fp16 features) ----------------

__global__ __launch_bounds__(256) void k_agg(const __half* __restrict__ h16,
                                             const int* __restrict__ row_ptr,
                                             const int* __restrict__ col,
                                             float* __restrict__ agg, int n) {
    int wid = (blockIdx.x * blockDim.x + threadIdx.x) >> 6;
    if (wid >= n) return;
    int lane = threadIdx.x & 63;
    int g = lane >> 3;   // edge slot (8)
    int p = lane & 7;    // dim oct: dims 8p..8p+7
    int beg = row_ptr[wid], end = row_ptr[wid + 1];

    float a0 = 0.f, a1 = 0.f, a2 = 0.f, a3 = 0.f;
    float a4 = 0.f, a5 = 0.f, a6 = 0.f, a7 = 0.f;

#define ACCUM(V)                                                          \
    {                                                                     \
        const __half2* q = (const __half2*)&(V);                          \
        float2 f0 = __half22float2(q[0]);                                 \
        float2 f1 = __half22float2(q[1]);                                 \
        float2 f2 = __half22float2(q[2]);                                 \
        float2 f3 = __half22float2(q[3]);                                 \
        a0 += f0.x; a1 += f0.y; a2 += f1.x; a3 += f1.y;                   \
        a4 += f2.x; a5 += f2.y; a6 += f3.x; a7 += f3.y;                   \
    }

    int j = beg + g;
    for (; j + 8 < end; j += 16) {
        int s0 = col[j];
        int s1 = col[j + 8];
        uint4 v0 = ((const uint4*)(h16 + (size_t)s0 * DIM))[p];
        uint4 v1 = ((const uint4*)(h16 + (size_t)s1 * DIM))[p];
        ACCUM(v0)
        ACCUM(v1)
    }
    if (j < end) {
        int s0 = col[j];
        uint4 v0 = ((const uint4*)(h16 + (size_t)s0 * DIM))[p];
        ACCUM(v0)
    }
#undef ACCUM

#pragma unroll
    for (int m = 8; m <= 32; m <<= 1) {
        a0 += __shfl_xor(a0, m, 64);
        a1 += __shfl_xor(a1, m, 64);
        a2 += __shfl_xor(a2, m, 64);
        a3 += __shfl_xor(a3, m, 64);
        a4 += __shfl_xor(a4, m, 64);
        a5 += __shfl_xor(a5, m, 64);
        a6 += __shfl_xor(a6, m, 64);
        a7 += __shfl_xor(a7, m, 64);
    }

    if (g == 0) {
        float c = (float)(end - beg);
        float inv = 1.0f / fmaxf(c, 1.0f);
        float4* op = (float4*)(agg + (size_t)wid * DIM + p * 8);
        float4 r0, r1;
        r0.x = a0 * inv; r0.y = a1 * inv; r0.z = a2 * inv; r0.w = a3 * inv;
        r1.x = a4 * inv; r1.y = a5 * inv; r1.z = a6 * inv; r1.w = a7 * inv;
        op[0] = r0;
        op[1] = r1;
    }
}

// ---------------- fused linear (agg@Wl + bl + h@Wr) + BN(eval) + ReLU ----------------

__global__ __launch_bounds__(256) void k_xform(const float* __restrict__ agg,
                                               const __half* __restrict__ h16,
                                               const float* __restrict__ Wl,
                                               const float* __restrict__ bl,
                                               const float* __restrict__ Wr,
                                               const float* __restrict__ bng,
                                               const float* __restrict__ bnb,
                                               const float* __restrict__ bnm,
                                               const float* __restrict__ bnv,
                                               __half* __restrict__ out16, int n) {
    __shared__ float4 sWl[64 * 16];
    __shared__ float4 sWr[64 * 16];
    __shared__ float4 sA[64 * XS];
    __shared__ float4 sH[64 * XS];
    int tid = threadIdx.x;
    int base = blockIdx.x * 64;
    int rows = min(64, n - base);

    const float4* Wl4 = (const float4*)Wl;
    const float4* Wr4 = (const float4*)Wr;
    const float4* A4 = (const float4*)(agg + (size_t)base * DIM);
    const uint2* H2 = (const uint2*)(h16 + (size_t)base * DIM);
    for (int i = tid; i < 1024; i += 256) {
        sWl[i] = Wl4[i];
        sWr[i] = Wr4[i];
        int row = i >> 4, c = i & 15;
        float4 va = {0.f, 0.f, 0.f, 0.f}, vh = {0.f, 0.f, 0.f, 0.f};
        if (row < rows) {
            va = A4[i];
            uint2 u = H2[i];
            const __half2* q = (const __half2*)&u;
            float2 lo = __half22float2(q[0]);
            float2 hi = __half22float2(q[1]);
            vh.x = lo.x; vh.y = lo.y; vh.z = hi.x; vh.w = hi.y;
        }
        sA[row * XS + c] = va;
        sH[row * XS + c] = vh;
    }
    __syncthreads();

    int dq = tid & 15;
    int nq = tid >> 4;
    float4 acc0 = {0.f, 0.f, 0.f, 0.f};
    float4 acc1 = {0.f, 0.f, 0.f, 0.f};
    float4 acc2 = {0.f, 0.f, 0.f, 0.f};
    float4 acc3 = {0.f, 0.f, 0.f, 0.f};

    int arow = nq * 4 * XS;
#pragma unroll 4
    for (int kg = 0; kg < 16; ++kg) {
        float4 wl0 = sWl[(kg * 4 + 0) * 16 + dq];
        float4 wl1 = sWl[(kg * 4 + 1) * 16 + dq];
        float4 wl2 = sWl[(kg * 4 + 2) * 16 + dq];
        float4 wl3 = sWl[(kg * 4 + 3) * 16 + dq];
        float4 wr0 = sWr[(kg * 4 + 0) * 16 + dq];
        float4 wr1 = sWr[(kg * 4 + 1) * 16 + dq];
        float4 wr2 = sWr[(kg * 4 + 2) * 16 + dq];
        float4 wr3 = sWr[(kg * 4 + 3) * 16 + dq];
        float4 a0 = sA[arow + 0 * XS + kg];
        float4 a1 = sA[arow + 1 * XS + kg];
        float4 a2 = sA[arow + 2 * XS + kg];
        float4 a3 = sA[arow + 3 * XS + kg];
        float4 h0 = sH[arow + 0 * XS + kg];
        float4 h1 = sH[arow + 1 * XS + kg];
        float4 h2 = sH[arow + 2 * XS + kg];
        float4 h3 = sH[arow + 3 * XS + kg];
#define ACC1(AC, AV, HV)                                                        \
        AC.x += AV.x * wl0.x + AV.y * wl1.x + AV.z * wl2.x + AV.w * wl3.x       \
              + HV.x * wr0.x + HV.y * wr1.x + HV.z * wr2.x + HV.w * wr3.x;      \
        AC.y += AV.x * wl0.y + AV.y * wl1.y + AV.z * wl2.y + AV.w * wl3.y       \
              + HV.x * wr0.y + HV.y * wr1.y + HV.z * wr2.y + HV.w * wr3.y;      \
        AC.z += AV.x * wl0.z + AV.y * wl1.z + AV.z * wl2.z + AV.w * wl3.z       \
              + HV.x * wr0.z + HV.y * wr1.z + HV.z * wr2.z + HV.w * wr3.z;      \
        AC.w += AV.x * wl0.w + AV.y * wl1.w + AV.z * wl2.w + AV.w * wl3.w       \
              + HV.x * wr0.w + HV.y * wr1.w + HV.z * wr2.w + HV.w * wr3.w;
        ACC1(acc0, a0, h0)
        ACC1(acc1, a1, h1)
        ACC1(acc2, a2, h2)
        ACC1(acc3, a3, h3)
#undef ACC1
    }

    float4 g4 = ((const float4*)bng)[dq];
    float4 v4 = ((const float4*)bnv)[dq];
    float4 be4 = ((const float4*)bnb)[dq];
    float4 rm4 = ((const float4*)bnm)[dq];
    float4 bi4 = ((const float4*)bl)[dq];
    float4 sc;
    sc.x = g4.x / sqrtf(v4.x + BN_EPS);
    sc.y = g4.y / sqrtf(v4.y + BN_EPS);
    sc.z = g4.z / sqrtf(v4.z + BN_EPS);
    sc.w = g4.w / sqrtf(v4.w + BN_EPS);

    float4* accp[4] = {&acc0, &acc1, &acc2, &acc3};
#pragma unroll
    for (int i = 0; i < 4; ++i) {
        int node = base + nq * 4 + i;
        if (node < n) {
            float4 a = *accp[i];
            float4 r;
            r.x = fmaxf((a.x + bi4.x - rm4.x) * sc.x + be4.x, 0.f);
            r.y = fmaxf((a.y + bi4.y - rm4.y) * sc.y + be4.y, 0.f);
            r.z = fmaxf((a.z + bi4.z - rm4.z) * sc.z + be4.z, 0.f);
            r.w = fmaxf((a.w + bi4.w - rm4.w) * sc.w + be4.w, 0.f);
            __half2 o01 = __float22half2_rn(make_float2(r.x, r.y));
            __half2 o23 = __float22half2_rn(make_float2(r.z, r.w));
            uint2 u;
            u.x = *(unsigned int*)&o01;
            u.y = *(unsigned int*)&o23;
            ((uint2*)(out16 + (size_t)node * DIM))[dq] = u;
        }
    }
}

// ---------------- global mean pool (batch sorted, fp16 features) ----------------

__global__ __launch_bounds__(256) void k_pool(const __half* __restrict__ h16,
                                              const int* __restrict__ batch,
                                              float* __restrict__ gsum,
                                              int* __restrict__ gcnt, int n) {
    int nw = gridDim.x * 4;
    int w = blockIdx.x * 4 + (threadIdx.x >> 6);
    int lane = threadIdx.x & 63;
    int chunk = (n + nw - 1) / nw;
    int s = w * chunk, e = min(s + chunk, n);
    if (s >= e) return;
    int cur = batch[s];
    float acc = 0.f;
    int cnt = 0;
    for (int i = s; i < e; ++i) {
        int g = batch[i];
        if (g != cur) {
            atomicAdd(&gsum[cur * DIM + lane], acc);
            if (lane == 0) atomicAdd(&gcnt[cur], cnt);
            acc = 0.f; cnt = 0; cur = g;
        }
        acc += __half2float(h16[(size_t)i * DIM + lane]);
        ++cnt;
    }
    atomicAdd(&gsum[cur * DIM + lane], acc);
    if (lane == 0) atomicAdd(&gcnt[cur], cnt);
}

// ---------------- classifier head ----------------

__global__ __launch_bounds__(256) void k_mlp(const float* __restrict__ gsum,
                                             const int* __restrict__ gcnt,
                                             const float* __restrict__ gattr,
                                             const float* __restrict__ W1,
                                             const float* __restrict__ b1,
                                             const float* __restrict__ W2,
                                             const float* __restrict__ b2,
                                             float* __restrict__ out) {
    __shared__ float emb[NGRAPH][DIM + GATTR];
    __shared__ float hid[NGRAPH][32];
    int tid = threadIdx.x;
    for (int i = tid; i < NGRAPH * DIM; i += 256) {
        int g = i >> 6, d = i & 63;
        float c = (float)gcnt[g];
        emb[g][d] = gsum[i] / fmaxf(c, 1.0f);
    }
    for (int i = tid; i < NGRAPH * GATTR; i += 256) {
        int g = i >> 2, d = i & 3;
        emb[g][DIM + d] = gattr[i];
    }
    __syncthreads();
    for (int t = tid; t < NGRAPH * 32; t += 256) {
        int g = t >> 5, j = t & 31;
        float a = b1[j];
        for (int k = 0; k < DIM + GATTR; ++k) a += emb[g][k] * W1[k * 32 + j];
        hid[g][j] = fmaxf(a, 0.f);
    }
    __syncthreads();
    {
        int g = tid >> 1, o = tid & 1;
        float a = b2[o];
        for (int k = 0; k < 32; ++k) a += hid[g][k] * W2[k * 2 + o];
        out[g * 2 + o] = a;
    }
}

extern "C" void kernel_launch(void* const* d_in, const int* in_sizes, int n_in,
                              void* d_out, int out_size, void* d_ws, size_t ws_size,
                              hipStream_t stream) {
    const float* x = (const float*)d_in[0];
    const int* ei = (const int*)d_in[1];
    const int* batch = (const int*)d_in[2];
    const float* gattr = (const float*)d_in[3];
    const int N = in_sizes[0] / DIM;
    const int E = in_sizes[1] / 2;
    const int* src = ei;
    const int* dst = ei + E;

    const float *Wl[3], *bl[3], *Wr[3], *bg[3], *bb[3], *bm[3], *bv[3];
    for (int l = 0; l < 3; ++l) {
        int base = 4 + l * 7;
        Wl[l] = (const float*)d_in[base + 0];
        bl[l] = (const float*)d_in[base + 1];
        Wr[l] = (const float*)d_in[base + 2];
        bg[l] = (const float*)d_in[base + 3];
        bb[l] = (const float*)d_in[base + 4];
        bm[l] = (const float*)d_in[base + 5];
        bv[l] = (const float*)d_in[base + 6];
    }
    const float* W1 = (const float*)d_in[25];
    const float* b1 = (const float*)d_in[26];
    const float* W2 = (const float*)d_in[27];
    const float* b2 = (const float*)d_in[28];

    char* ws = (char*)d_ws;
    size_t off = 0;
    auto alloc = [&](size_t bytes) -> char* {
        char* p = ws + off;
        off += (bytes + 255) & ~(size_t)255;
        return p;
    };
    const int nb = (E + SCHUNK - 1) / SCHUNK;              // binning blocks (306)
    const int nbuck = (N + BUCKET - 1) >> BUCKET_SHIFT;    // buckets (782)
    const int total_h = nbuck * nb;                        // hist entries (~239K)

    int* rowptr = (int*)alloc((size_t)(N + 1) * 4);
    int* col = (int*)alloc((size_t)E * 4);
    int* hist = (int*)alloc((size_t)total_h * 4);
    float* aggb = (float*)alloc((size_t)N * DIM * 4);
    __half* x16 = (__half*)alloc((size_t)N * DIM * 2);
    __half* h16a = (__half*)alloc((size_t)N * DIM * 2);
    __half* h16b = (__half*)alloc((size_t)N * DIM * 2);
    float* gsum = (float*)alloc((size_t)NGRAPH * DIM * 4);
    int* gcnt = (int*)alloc((size_t)NGRAPH * 4);
    int* partials = (int*)alloc(1024 * 4);
    int2* pairs = (int2*)aggb;  // scratch reuse: consumed by k_bsort before k_agg writes aggb
    (void)ws_size;

    const int tpb = 256;
    const int nscanH = (total_h + SCAN_CHUNK - 1) / SCAN_CHUNK;  // 59

    k_zero<<<(NGRAPH * DIM + tpb - 1) / tpb, tpb, 0, stream>>>(gsum, gcnt);
    k_cast<<<1024, tpb, 0, stream>>>((const float4*)x, (uint2*)x16, N * DIM / 4);

    k_bhist<<<nb, tpb, 0, stream>>>(dst, hist, E, nb, nbuck);
    k_gscan1<<<nscanH, tpb, 0, stream>>>(hist, hist, partials, total_h);
    k_gscan23<<<nscanH, tpb, 0, stream>>>(hist, partials, total_h);
    k_sbin<<<nb, tpb, 0, stream>>>(src, dst, hist, pairs, E, nb, nbuck);
    k_bsort<<<nbuck, tpb, 0, stream>>>(pairs, hist, rowptr, col, N, nb, nbuck, E);

    const __half* hin = x16;
    __half* houts[3] = {h16a, h16b, h16a};
    for (int l = 0; l < 3; ++l) {
        k_agg<<<(N * 64 + tpb - 1) / tpb, tpb, 0, stream>>>(hin, rowptr, col, aggb, N);
        k_xform<<<(N + 63) / 64, 256, 0, stream>>>(aggb, hin, Wl[l], bl[l], Wr[l],
                                                   bg[l], bb[l], bm[l], bv[l], houts[l], N);
        hin = houts[l];
    }

    k_pool<<<256, tpb, 0, stream>>>(hin, batch, gsum, gcnt, N);
    k_mlp<<<1, tpb, 0, stream>>>(gsum, gcnt, gattr, W1, b1, W2, b2, (float*)d_out);
}